// Round 7
// baseline (279.156 us; speedup 1.0000x reference)
//
#include <hip/hip_runtime.h>
#include <hip/hip_bf16.h>

constexpr int N_NODES = 40000;
constexpr int N_EDGES = 640000;
constexpr int D = 128;
constexpr float BN_EPS = 1e-5f;
constexpr int CAP = 128;          // per-node edge bucket capacity (max deg ~40)
constexpr int NTILES = 1250;      // 625 rowtiles x 2 col-halves
constexpr int NCOLOR = 8;         // XCD colors
constexpr int NODES_PER_COLOR = N_NODES / NCOLOR;   // 5000
constexpr int FILL_BLOCKS = 2560; // 8 colors x 320 ranks
constexpr int COLOR_STRIDE = (FILL_BLOCKS / NCOLOR) * 256;  // 81920
constexpr int NREP = 16;          // BN partial replicas (atomic de-contention)
constexpr int FGRID = 625;        // fused gemm+final grid: tiles b and b+625
                                  // co-residency: launch_bounds(256,3) -> >=3
                                  // blocks/CU (LDS 33.5KB -> 4/CU), 768 >= 625

typedef __attribute__((ext_vector_type(8))) short short8;
typedef __attribute__((ext_vector_type(4))) float f32x4;
typedef __attribute__((ext_vector_type(2))) float f32x2;

__device__ __forceinline__ unsigned bf16_rne(float f) {
    unsigned b = __float_as_uint(f);
    return (b + 0x7FFFu + ((b >> 16) & 1u)) >> 16;
}
__device__ __forceinline__ float bflo(unsigned w) { return __uint_as_float(w << 16); }
__device__ __forceinline__ float bfhi(unsigned w) { return __uint_as_float(w & 0xFFFF0000u); }

// ---------------------------------------------------------------------------
// K1: fused h->bf16 + h->fp8 / W->frag-major conversion + XCD-COLORED bucket
// fill. (unchanged from round 5)
// ---------------------------------------------------------------------------
__global__ __launch_bounds__(256) void cvt_fill_kernel(
        const int* __restrict__ dst,
        const int* __restrict__ src,
        int* __restrict__ cursor,
        int* __restrict__ esrc,
        const float4* __restrict__ h4,
        uint4* __restrict__ hb4,
        uint2* __restrict__ hb8,
        const float* __restrict__ Wself,
        const float* __restrict__ Wneigh,
        uint4* __restrict__ wfrag) {
    int gid = blockIdx.x * blockDim.x + threadIdx.x;

    if (gid < N_EDGES) {
        float4 a = h4[2 * gid];
        float4 b = h4[2 * gid + 1];
        uint4 o;
        o.x = bf16_rne(a.x) | (bf16_rne(a.y) << 16);
        o.y = bf16_rne(a.z) | (bf16_rne(a.w) << 16);
        o.z = bf16_rne(b.x) | (bf16_rne(b.y) << 16);
        o.w = bf16_rne(b.z) | (bf16_rne(b.w) << 16);
        hb4[gid] = o;
        unsigned w0 = __builtin_amdgcn_cvt_pk_fp8_f32(a.x, a.y, 0, false);
        w0 = __builtin_amdgcn_cvt_pk_fp8_f32(a.z, a.w, w0, true);
        unsigned w1 = __builtin_amdgcn_cvt_pk_fp8_f32(b.x, b.y, 0, false);
        w1 = __builtin_amdgcn_cvt_pk_fp8_f32(b.z, b.w, w1, true);
        uint2 o8; o8.x = w0; o8.y = w1;
        hb8[gid] = o8;
    }
    // W -> frag-major bf16: granule G=(ct*8+kt)*64+kg*16+n holds j=0..7 of
    // Wcat[k=kt*32+kg*8+j][col=ct*16+n], Wcat=[Wself;Wneigh] (K=256).
    if (gid < 4096) {
        int G = gid;
        int l = G & 63;
        int tile = G >> 6;
        int kg = l >> 4, n = l & 15;
        int ct = tile >> 3, kt = tile & 7;
        int k0 = kt * 32 + kg * 8;
        int col = ct * 16 + n;
        unsigned w[8];
        #pragma unroll
        for (int j = 0; j < 8; j++) {
            int k = k0 + j;
            float v = (k < D) ? Wself[(size_t)k * D + col]
                              : Wneigh[(size_t)(k - D) * D + col];
            w[j] = bf16_rne(v);
        }
        uint4 ow;
        ow.x = w[0] | (w[1] << 16);
        ow.y = w[2] | (w[3] << 16);
        ow.z = w[4] | (w[5] << 16);
        ow.w = w[6] | (w[7] << 16);
        wfrag[G] = ow;
    }

    // colored bucket fill
    int c = blockIdx.x & (NCOLOR - 1);
    int lo = c * NODES_PER_COLOR;
    int hi = lo + NODES_PER_COLOR;
    int base = (blockIdx.x >> 3) * 256 + threadIdx.x;
    for (int e = base; e < N_EDGES; e += COLOR_STRIDE) {
        int t = dst[e];
        if (t >= lo && t < hi) {
            int s = src[e];
            int p = atomicAdd(&cursor[t], 1);
            if (p < CAP) esrc[t * CAP + p] = s;
        }
    }
}

// ---------------------------------------------------------------------------
// K2: gather + mean from fp8 rows, one wave per node, COLOR-PINNED.
// (unchanged from round 5 -- 40000-wave TLP is essential, rounds 4/6 proved
// merging this into the GEMM loses)
// ---------------------------------------------------------------------------
__global__ __launch_bounds__(256) void gather_kernel(
        const uint4* __restrict__ hb8q,   // 8 uint4 per node row (128 fp8)
        const int* __restrict__ cursor,
        const int* __restrict__ esrc,
        uint4* __restrict__ hnb4) {
    int c = blockIdx.x & (NCOLOR - 1);
    int rank = blockIdx.x >> 3;           // 0..1249
    int wid = threadIdx.x >> 6;
    int node = c * NODES_PER_COLOR + rank * 4 + wid;
    int lane = threadIdx.x & 63;
    int g  = lane & 7;        // 16-col group
    int es = lane >> 3;       // 8 edge slices
    int deg = cursor[node];
    int cnt = deg < CAP ? deg : CAP;
    const int* bucket = esrc + node * CAP;
    float acc[16];
    #pragma unroll
    for (int i = 0; i < 16; i++) acc[i] = 0.f;
    for (int j = es; j < cnt; j += 8) {
        int a = bucket[j];
        uint4 v = hb8q[(size_t)a * 8 + g];
        f32x2 f;
        f = __builtin_amdgcn_cvt_pk_f32_fp8(v.x, false); acc[0]  += f.x; acc[1]  += f.y;
        f = __builtin_amdgcn_cvt_pk_f32_fp8(v.x, true);  acc[2]  += f.x; acc[3]  += f.y;
        f = __builtin_amdgcn_cvt_pk_f32_fp8(v.y, false); acc[4]  += f.x; acc[5]  += f.y;
        f = __builtin_amdgcn_cvt_pk_f32_fp8(v.y, true);  acc[6]  += f.x; acc[7]  += f.y;
        f = __builtin_amdgcn_cvt_pk_f32_fp8(v.z, false); acc[8]  += f.x; acc[9]  += f.y;
        f = __builtin_amdgcn_cvt_pk_f32_fp8(v.z, true);  acc[10] += f.x; acc[11] += f.y;
        f = __builtin_amdgcn_cvt_pk_f32_fp8(v.w, false); acc[12] += f.x; acc[13] += f.y;
        f = __builtin_amdgcn_cvt_pk_f32_fp8(v.w, true);  acc[14] += f.x; acc[15] += f.y;
    }
    #pragma unroll
    for (int i = 0; i < 16; i++) {
        acc[i] += __shfl_xor(acc[i], 8);
        acc[i] += __shfl_xor(acc[i], 16);
        acc[i] += __shfl_xor(acc[i], 32);
    }
    if (es == 0) {
        float rd = 1.0f / (float)(deg > 1 ? deg : 1);
        uint4 o0, o1;
        o0.x = bf16_rne(acc[0] * rd)  | (bf16_rne(acc[1] * rd)  << 16);
        o0.y = bf16_rne(acc[2] * rd)  | (bf16_rne(acc[3] * rd)  << 16);
        o0.z = bf16_rne(acc[4] * rd)  | (bf16_rne(acc[5] * rd)  << 16);
        o0.w = bf16_rne(acc[6] * rd)  | (bf16_rne(acc[7] * rd)  << 16);
        o1.x = bf16_rne(acc[8] * rd)  | (bf16_rne(acc[9] * rd)  << 16);
        o1.y = bf16_rne(acc[10] * rd) | (bf16_rne(acc[11] * rd) << 16);
        o1.z = bf16_rne(acc[12] * rd) | (bf16_rne(acc[13] * rd) << 16);
        o1.w = bf16_rne(acc[14] * rd) | (bf16_rne(acc[15] * rd) << 16);
        hnb4[(size_t)node * 16 + g * 2]     = o0;
        hnb4[(size_t)node * 16 + g * 2 + 1] = o1;
    }
}

// ---------------------------------------------------------------------------
// K3: fused MFMA dual GEMM + BN + residual finalize via software grid
// barrier. 625 blocks, each computes tiles b and b+625 (opposite col-halves),
// keeps post-relu-snorm values in registers (v0/v1), flushes BN partials to
// 16 replicas, ticket+spin until all 625 blocks arrive, then reduces the
// replicas with agent-scope atomic loads and finalizes
// out = h + v*sc + (beta - m*sc) straight from registers.
// No preb roundtrip, no 4th dispatch. No bf16 quantization of pre.
// ---------------------------------------------------------------------------
__device__ __forceinline__ void compute_tile(
        int tile, int t, int lane, int wid, int n, int kg, int rep,
        const uint4* __restrict__ hb4,
        const uint4* __restrict__ hnb4,
        const uint4* __restrict__ wfrag,
        const float* __restrict__ snorm,
        const float* __restrict__ bias,
        float* __restrict__ sums_r,
        float* __restrict__ sumsq_r,
        uint4* ldsW, float* sums_l, float* sumsq_l,
        float (&v)[16]) {
    int rowtile = tile >> 1;
    int cbt = tile & 1;
    int cb = cbt * 64;
    int row_base = rowtile * 64 + wid * 16;
    int row = row_base + n;

    if (t < 64) { sums_l[t] = 0.f; sumsq_l[t] = 0.f; }
    #pragma unroll
    for (int i = 0; i < 8; i++) {
        int g = i * 256 + t;
        ldsW[g] = wfrag[cbt * 2048 + g];
    }

    short8 a[8];
    #pragma unroll
    for (int kt = 0; kt < 4; kt++)
        a[kt] = __builtin_bit_cast(short8, hb4[(size_t)row * 16 + kt * 4 + kg]);
    #pragma unroll
    for (int kt = 0; kt < 4; kt++)
        a[4 + kt] = __builtin_bit_cast(short8, hnb4[(size_t)row * 16 + kt * 4 + kg]);

    __syncthreads();

    f32x4 acc[4];
    #pragma unroll
    for (int lt = 0; lt < 4; lt++) acc[lt] = (f32x4){0.f, 0.f, 0.f, 0.f};
    #pragma unroll
    for (int lt = 0; lt < 4; lt++) {
        #pragma unroll
        for (int kt = 0; kt < 8; kt++) {
            short8 b = __builtin_bit_cast(short8, ldsW[(lt * 8 + kt) * 64 + lane]);
            acc[lt] = __builtin_amdgcn_mfma_f32_16x16x32_bf16(a[kt], b, acc[lt], 0, 0, 0);
        }
    }

    float snv[4];
    #pragma unroll
    for (int r = 0; r < 4; r++) snv[r] = snorm[row_base + kg * 4 + r];

    #pragma unroll
    for (int lt = 0; lt < 4; lt++) {
        int col = cb + lt * 16 + n;
        float bb = bias[col];
        float csum = 0.f, csq = 0.f;
        #pragma unroll
        for (int r = 0; r < 4; r++) {
            float x = acc[lt][r] + bb;
            x = fmaxf(x, 0.f);
            x *= snv[r];
            v[lt * 4 + r] = x;
            csum += x;
            csq += x * x;
        }
        csum += __shfl_xor(csum, 16); csq += __shfl_xor(csq, 16);
        csum += __shfl_xor(csum, 32); csq += __shfl_xor(csq, 32);
        if (kg == 0) {
            atomicAdd(&sums_l[lt * 16 + n], csum);
            atomicAdd(&sumsq_l[lt * 16 + n], csq);
        }
    }
    __syncthreads();
    if (t < 64) {
        atomicAdd(&sums_r[rep * D + cb + t], sums_l[t]);
        atomicAdd(&sumsq_r[rep * D + cb + t], sumsq_l[t]);
    }
    __syncthreads();   // sums_l reads done before next tile re-zeros / barrier
}

__global__ __launch_bounds__(256, 3) void gemm_final_kernel(
        const uint4* __restrict__ hb4,
        const uint4* __restrict__ hnb4,
        const uint4* __restrict__ wfrag,
        const float* __restrict__ snorm,
        const float* __restrict__ bias,
        const float* __restrict__ gamma,
        const float* __restrict__ beta,
        const float* __restrict__ h,
        float* __restrict__ sums_r,
        float* __restrict__ sumsq_r,
        int* __restrict__ done,
        float* __restrict__ out) {
    __shared__ uint4 ldsW[2048];
    __shared__ float sums_l[64];
    __shared__ float sumsq_l[64];
    __shared__ float colA[128];     // sc
    __shared__ float colB[128];     // beta - m*sc

    int t = threadIdx.x;
    int lane = t & 63;
    int wid = t >> 6;
    int n = lane & 15;
    int kg = lane >> 4;
    int rep = blockIdx.x & (NREP - 1);

    int tile0 = blockIdx.x;           // col-half b&1
    int tile1 = blockIdx.x + FGRID;   // opposite col-half

    float v0[16], v1[16];
    compute_tile(tile0, t, lane, wid, n, kg, rep, hb4, hnb4, wfrag, snorm,
                 bias, sums_r, sumsq_r, ldsW, sums_l, sumsq_l, v0);
    compute_tile(tile1, t, lane, wid, n, kg, rep, hb4, hnb4, wfrag, snorm,
                 bias, sums_r, sumsq_r, ldsW, sums_l, sumsq_l, v1);

    // ---- software grid barrier ----
    __threadfence();                  // all global atomics globally visible
    __syncthreads();                  // every thread of block past its flush
    if (t == 0) {
        __hip_atomic_fetch_add(done, 1, __ATOMIC_ACQ_REL,
                               __HIP_MEMORY_SCOPE_AGENT);
        while (__hip_atomic_load(done, __ATOMIC_ACQUIRE,
                                 __HIP_MEMORY_SCOPE_AGENT) < FGRID)
            __builtin_amdgcn_s_sleep(8);
    }
    __syncthreads();

    // ---- replica reduce: thread t<128 owns column t ----
    if (t < 128) {
        float s = 0.f, q = 0.f;
        #pragma unroll
        for (int r = 0; r < NREP; r++) {
            s += __hip_atomic_load(&sums_r[r * D + t], __ATOMIC_RELAXED,
                                   __HIP_MEMORY_SCOPE_AGENT);
            q += __hip_atomic_load(&sumsq_r[r * D + t], __ATOMIC_RELAXED,
                                   __HIP_MEMORY_SCOPE_AGENT);
        }
        const float invN = 1.0f / (float)N_NODES;
        float m = s * invN;
        float var = q * invN - m * m;
        float sc = gamma[t] * rsqrtf(var + BN_EPS);
        colA[t] = sc;
        colB[t] = beta[t] - m * sc;
    }
    __syncthreads();

    // ---- finalize from registers ----
    #pragma unroll
    for (int half = 0; half < 2; half++) {
        int tile = half == 0 ? tile0 : tile1;
        const float (&v)[16] = half == 0 ? v0 : v1;
        int rowtile = tile >> 1;
        int cb = (tile & 1) * 64;
        int row_base = rowtile * 64 + wid * 16;
        #pragma unroll
        for (int lt = 0; lt < 4; lt++) {
            int col = cb + lt * 16 + n;
            float A = colA[col];
            float B = colB[col];
            #pragma unroll
            for (int r = 0; r < 4; r++) {
                int rr = row_base + kg * 4 + r;
                out[(size_t)rr * D + col] =
                    h[(size_t)rr * D + col] + v[lt * 4 + r] * A + B;
            }
        }
    }
}

// ---------------------------------------------------------------------------
extern "C" void kernel_launch(void* const* d_in, const int* in_sizes, int n_in,
                              void* d_out, int out_size, void* d_ws, size_t ws_size,
                              hipStream_t stream) {
    const float* h      = (const float*)d_in[0];
    const float* snorm  = (const float*)d_in[1];
    const float* Wself  = (const float*)d_in[2];
    const float* Wneigh = (const float*)d_in[3];
    const float* bias   = (const float*)d_in[4];
    const float* gamma  = (const float*)d_in[5];
    const float* beta   = (const float*)d_in[6];
    const int*   src    = (const int*)d_in[7];
    const int*   dst    = (const int*)d_in[8];
    float* out = (float*)d_out;

    // ws layout:
    // zeroed:   [ cursor : N int ][ sums_r : 16*D f ][ sumsq_r : 16*D f ][ done : 1 int ]
    // unzeroed: [ esrc : N*CAP int = 20.5MB ][ wfrag : 64KB ]
    //           [ hb : 10.2MB ][ hnb : 10.2MB ][ hb8 : 5.1MB ]
    int*   cursor  = (int*)d_ws;
    float* sums_r  = (float*)(cursor + N_NODES);
    float* sumsq_r = sums_r + NREP * D;
    int*   done    = (int*)(sumsq_r + NREP * D);
    int*   esrc    = done + 1;
    size_t off     = (size_t)((char*)(esrc + (size_t)N_NODES * CAP) - (char*)d_ws);
    off = (off + 15) & ~(size_t)15;
    uint4* wfrag = (uint4*)((char*)d_ws + off);
    uint4* hb4   = wfrag + 4096;
    uint4* hnb4  = hb4 + N_NODES * (D / 8);
    uint2* hb8   = (uint2*)(hnb4 + N_NODES * (D / 8));

    size_t zero_bytes = (size_t)(N_NODES + 2 * NREP * D + 1) * sizeof(float);
    hipMemsetAsync(d_ws, 0, zero_bytes, stream);

    // K1: colored bucket fill + h -> bf16/fp8 + W -> frag-major bf16
    cvt_fill_kernel<<<FILL_BLOCKS, 256, 0, stream>>>(
        dst, src, cursor, esrc, (const float4*)h, hb4, hb8, Wself, Wneigh, wfrag);
    // K2: gather + mean from fp8 -> hnb (bf16), one wave per node, color-pinned
    gather_kernel<<<N_NODES / 4, 256, 0, stream>>>(
        (const uint4*)hb8, cursor, esrc, hnb4);
    // K3: fused dual GEMM + BN (software grid barrier) + residual -> d_out
    gemm_final_kernel<<<FGRID, 256, 0, stream>>>(
        hb4, hnb4, wfrag, snorm, bias, gamma, beta, h,
        sums_r, sumsq_r, done, out);
}

// Round 9
// 177.646 us; speedup vs baseline: 1.5714x; 1.5714x over previous
//
#include <hip/hip_runtime.h>
#include <hip/hip_bf16.h>

constexpr int N_NODES = 40000;
constexpr int N_EDGES = 640000;
constexpr int D = 128;
constexpr float BN_EPS = 1e-5f;
constexpr int CAP = 128;          // per-node edge bucket capacity (max deg ~40)
constexpr int NTILES = 1250;      // 625 rowtiles x 2 col-halves
constexpr int NCOLOR = 8;         // XCD colors
constexpr int NODES_PER_COLOR = N_NODES / NCOLOR;   // 5000
constexpr int FILL_BLOCKS = 2560; // 8 colors x 320 ranks
constexpr int COLOR_STRIDE = (FILL_BLOCKS / NCOLOR) * 256;  // 81920
constexpr int NREP = 16;          // BN partial replicas (atomic de-contention)
constexpr int CSTRIDE = 32;       // cursor padding: 1 counter per 128B line

typedef __attribute__((ext_vector_type(8))) short short8;
typedef __attribute__((ext_vector_type(4))) float f32x4;
typedef __attribute__((ext_vector_type(2))) float f32x2;

__device__ __forceinline__ unsigned bf16_rne(float f) {
    unsigned b = __float_as_uint(f);
    return (b + 0x7FFFu + ((b >> 16) & 1u)) >> 16;
}
__device__ __forceinline__ float bflo(unsigned w) { return __uint_as_float(w << 16); }
__device__ __forceinline__ float bfhi(unsigned w) { return __uint_as_float(w & 0xFFFF0000u); }

// ---------------------------------------------------------------------------
// K1: fused h->bf16 + h->fp8 / W->frag-major conversion + XCD-COLORED bucket
// fill. NEW vs round 5: cursor padded to 1 counter / 128B line (CSTRIDE) to
// kill TCC line-granular RMW serialization on the 640K atomicAdds.
// ---------------------------------------------------------------------------
__global__ __launch_bounds__(256) void cvt_fill_kernel(
        const int* __restrict__ dst,
        const int* __restrict__ src,
        int* __restrict__ cursor,
        int* __restrict__ esrc,
        const float4* __restrict__ h4,
        uint4* __restrict__ hb4,
        uint2* __restrict__ hb8,
        const float* __restrict__ Wself,
        const float* __restrict__ Wneigh,
        uint4* __restrict__ wfrag) {
    int gid = blockIdx.x * blockDim.x + threadIdx.x;

    if (gid < N_EDGES) {
        float4 a = h4[2 * gid];
        float4 b = h4[2 * gid + 1];
        uint4 o;
        o.x = bf16_rne(a.x) | (bf16_rne(a.y) << 16);
        o.y = bf16_rne(a.z) | (bf16_rne(a.w) << 16);
        o.z = bf16_rne(b.x) | (bf16_rne(b.y) << 16);
        o.w = bf16_rne(b.z) | (bf16_rne(b.w) << 16);
        hb4[gid] = o;
        unsigned w0 = __builtin_amdgcn_cvt_pk_fp8_f32(a.x, a.y, 0, false);
        w0 = __builtin_amdgcn_cvt_pk_fp8_f32(a.z, a.w, w0, true);
        unsigned w1 = __builtin_amdgcn_cvt_pk_fp8_f32(b.x, b.y, 0, false);
        w1 = __builtin_amdgcn_cvt_pk_fp8_f32(b.z, b.w, w1, true);
        uint2 o8; o8.x = w0; o8.y = w1;
        hb8[gid] = o8;
    }
    // W -> frag-major bf16: granule G=(ct*8+kt)*64+kg*16+n holds j=0..7 of
    // Wcat[k=kt*32+kg*8+j][col=ct*16+n], Wcat=[Wself;Wneigh] (K=256).
    if (gid < 4096) {
        int G = gid;
        int l = G & 63;
        int tile = G >> 6;
        int kg = l >> 4, n = l & 15;
        int ct = tile >> 3, kt = tile & 7;
        int k0 = kt * 32 + kg * 8;
        int col = ct * 16 + n;
        unsigned w[8];
        #pragma unroll
        for (int j = 0; j < 8; j++) {
            int k = k0 + j;
            float v = (k < D) ? Wself[(size_t)k * D + col]
                              : Wneigh[(size_t)(k - D) * D + col];
            w[j] = bf16_rne(v);
        }
        uint4 ow;
        ow.x = w[0] | (w[1] << 16);
        ow.y = w[2] | (w[3] << 16);
        ow.z = w[4] | (w[5] << 16);
        ow.w = w[6] | (w[7] << 16);
        wfrag[G] = ow;
    }

    // colored bucket fill
    int c = blockIdx.x & (NCOLOR - 1);
    int lo = c * NODES_PER_COLOR;
    int hi = lo + NODES_PER_COLOR;
    int base = (blockIdx.x >> 3) * 256 + threadIdx.x;
    for (int e = base; e < N_EDGES; e += COLOR_STRIDE) {
        int t = dst[e];
        if (t >= lo && t < hi) {
            int s = src[e];
            int p = atomicAdd(&cursor[(size_t)t * CSTRIDE], 1);
            if (p < CAP) esrc[t * CAP + p] = s;
        }
    }
}

// ---------------------------------------------------------------------------
// K2: gather + mean from fp8 rows, one wave per node, COLOR-PINNED.
// (round-5 version; reads padded cursor)
// ---------------------------------------------------------------------------
__global__ __launch_bounds__(256) void gather_kernel(
        const uint4* __restrict__ hb8q,   // 8 uint4 per node row (128 fp8)
        const int* __restrict__ cursor,
        const int* __restrict__ esrc,
        uint4* __restrict__ hnb4) {
    int c = blockIdx.x & (NCOLOR - 1);
    int rank = blockIdx.x >> 3;           // 0..1249
    int wid = threadIdx.x >> 6;
    int node = c * NODES_PER_COLOR + rank * 4 + wid;
    int lane = threadIdx.x & 63;
    int g  = lane & 7;        // 16-col group
    int es = lane >> 3;       // 8 edge slices
    int deg = cursor[(size_t)node * CSTRIDE];
    int cnt = deg < CAP ? deg : CAP;
    const int* bucket = esrc + node * CAP;
    float acc[16];
    #pragma unroll
    for (int i = 0; i < 16; i++) acc[i] = 0.f;
    for (int j = es; j < cnt; j += 8) {
        int a = bucket[j];
        uint4 v = hb8q[(size_t)a * 8 + g];
        f32x2 f;
        f = __builtin_amdgcn_cvt_pk_f32_fp8(v.x, false); acc[0]  += f.x; acc[1]  += f.y;
        f = __builtin_amdgcn_cvt_pk_f32_fp8(v.x, true);  acc[2]  += f.x; acc[3]  += f.y;
        f = __builtin_amdgcn_cvt_pk_f32_fp8(v.y, false); acc[4]  += f.x; acc[5]  += f.y;
        f = __builtin_amdgcn_cvt_pk_f32_fp8(v.y, true);  acc[6]  += f.x; acc[7]  += f.y;
        f = __builtin_amdgcn_cvt_pk_f32_fp8(v.z, false); acc[8]  += f.x; acc[9]  += f.y;
        f = __builtin_amdgcn_cvt_pk_f32_fp8(v.z, true);  acc[10] += f.x; acc[11] += f.y;
        f = __builtin_amdgcn_cvt_pk_f32_fp8(v.w, false); acc[12] += f.x; acc[13] += f.y;
        f = __builtin_amdgcn_cvt_pk_f32_fp8(v.w, true);  acc[14] += f.x; acc[15] += f.y;
    }
    #pragma unroll
    for (int i = 0; i < 16; i++) {
        acc[i] += __shfl_xor(acc[i], 8);
        acc[i] += __shfl_xor(acc[i], 16);
        acc[i] += __shfl_xor(acc[i], 32);
    }
    if (es == 0) {
        float rd = 1.0f / (float)(deg > 1 ? deg : 1);
        uint4 o0, o1;
        o0.x = bf16_rne(acc[0] * rd)  | (bf16_rne(acc[1] * rd)  << 16);
        o0.y = bf16_rne(acc[2] * rd)  | (bf16_rne(acc[3] * rd)  << 16);
        o0.z = bf16_rne(acc[4] * rd)  | (bf16_rne(acc[5] * rd)  << 16);
        o0.w = bf16_rne(acc[6] * rd)  | (bf16_rne(acc[7] * rd)  << 16);
        o1.x = bf16_rne(acc[8] * rd)  | (bf16_rne(acc[9] * rd)  << 16);
        o1.y = bf16_rne(acc[10] * rd) | (bf16_rne(acc[11] * rd) << 16);
        o1.z = bf16_rne(acc[12] * rd) | (bf16_rne(acc[13] * rd) << 16);
        o1.w = bf16_rne(acc[14] * rd) | (bf16_rne(acc[15] * rd) << 16);
        hnb4[(size_t)node * 16 + g * 2]     = o0;
        hnb4[(size_t)node * 16 + g * 2 + 1] = o1;
    }
}

// ---------------------------------------------------------------------------
// K3: MFMA dual GEMM (round-5 version). BN partials to 16 replicas
// (replica = blockIdx&15). pre stored bf16 in ws.
// ---------------------------------------------------------------------------
__global__ __launch_bounds__(256) void gemm_kernel(
        const uint4* __restrict__ hb4,
        const uint4* __restrict__ hnb4,
        const uint4* __restrict__ wfrag,
        const float* __restrict__ snorm,
        const float* __restrict__ bias,
        ushort* __restrict__ preb,          // bf16 pre (ws)
        float* __restrict__ sums_r,         // [NREP][D]
        float* __restrict__ sumsq_r) {      // [NREP][D]
    __shared__ uint4 ldsW[2048];
    __shared__ float sums_l[64];
    __shared__ float sumsq_l[64];

    int t = threadIdx.x;
    int lane = t & 63;
    int wid = t >> 6;
    int n = lane & 15;
    int kg = lane >> 4;
    int rowtile = blockIdx.x >> 1;
    int cbt = blockIdx.x & 1;
    int cb = cbt * 64;
    int row_base = rowtile * 64 + wid * 16;
    int row = row_base + n;

    if (t < 64) { sums_l[t] = 0.f; sumsq_l[t] = 0.f; }

    short8 a[8];
    #pragma unroll
    for (int kt = 0; kt < 4; kt++) {
        uint4 v = hb4[(size_t)row * 16 + kt * 4 + kg];
        a[kt] = __builtin_bit_cast(short8, v);
    }
    #pragma unroll
    for (int kt = 0; kt < 4; kt++) {
        uint4 v = hnb4[(size_t)row * 16 + kt * 4 + kg];
        a[4 + kt] = __builtin_bit_cast(short8, v);
    }

    #pragma unroll
    for (int i = 0; i < 8; i++) {
        int g = i * 256 + t;
        ldsW[g] = wfrag[cbt * 2048 + g];
    }
    __syncthreads();

    f32x4 acc[4];
    #pragma unroll
    for (int lt = 0; lt < 4; lt++) acc[lt] = (f32x4){0.f, 0.f, 0.f, 0.f};
    #pragma unroll
    for (int lt = 0; lt < 4; lt++) {
        #pragma unroll
        for (int kt = 0; kt < 8; kt++) {
            short8 b = __builtin_bit_cast(short8, ldsW[(lt * 8 + kt) * 64 + lane]);
            acc[lt] = __builtin_amdgcn_mfma_f32_16x16x32_bf16(a[kt], b, acc[lt], 0, 0, 0);
        }
    }

    float snv[4];
    #pragma unroll
    for (int r = 0; r < 4; r++) snv[r] = snorm[row_base + kg * 4 + r];

    #pragma unroll
    for (int lt = 0; lt < 4; lt++) {
        int col = cb + lt * 16 + n;
        float bb = bias[col];
        float csum = 0.f, csq = 0.f;
        #pragma unroll
        for (int r = 0; r < 4; r++) {
            int rr = row_base + kg * 4 + r;
            float v = acc[lt][r] + bb;
            v = fmaxf(v, 0.f);
            v *= snv[r];
            preb[(size_t)rr * D + col] = (ushort)bf16_rne(v);
            csum += v;
            csq += v * v;
        }
        csum += __shfl_xor(csum, 16); csq += __shfl_xor(csq, 16);
        csum += __shfl_xor(csum, 32); csq += __shfl_xor(csq, 32);
        if (kg == 0) {
            atomicAdd(&sums_l[lt * 16 + n], csum);
            atomicAdd(&sumsq_l[lt * 16 + n], csq);
        }
    }
    __syncthreads();
    if (t < 64) {
        int rep = blockIdx.x & (NREP - 1);
        atomicAdd(&sums_r[rep * D + cb + t], sums_l[t]);
        atomicAdd(&sumsq_r[rep * D + cb + t], sumsq_l[t]);
    }
}

// ---------------------------------------------------------------------------
// K4: finalize: replica-reduce (16) + residual + BN from bf16 pre -> d_out.
// (round-5 version with NREP=16)
// ---------------------------------------------------------------------------
__global__ __launch_bounds__(256) void final_kernel(
        const float4* __restrict__ h4,
        const float4* __restrict__ sums_r4,    // [NREP][32] float4
        const float4* __restrict__ sumsq_r4,   // [NREP][32] float4
        const float4* __restrict__ gamma4,
        const float4* __restrict__ beta4,
        const uint4* __restrict__ preb4,
        float4* __restrict__ out4) {
    int idx = blockIdx.x * blockDim.x + threadIdx.x;
    int total = N_NODES * D / 8;
    if (idx >= total) return;
    int g = idx & 15;                       // col-group of 8 within the row
    const float invN = 1.0f / (float)N_NODES;

    float4 s0 = {0.f,0.f,0.f,0.f}, s1 = {0.f,0.f,0.f,0.f};
    float4 q0 = {0.f,0.f,0.f,0.f}, q1 = {0.f,0.f,0.f,0.f};
    #pragma unroll
    for (int r = 0; r < NREP; r++) {
        float4 a0 = sums_r4[r * 32 + 2 * g],  a1 = sums_r4[r * 32 + 2 * g + 1];
        float4 c0 = sumsq_r4[r * 32 + 2 * g], c1 = sumsq_r4[r * 32 + 2 * g + 1];
        s0.x += a0.x; s0.y += a0.y; s0.z += a0.z; s0.w += a0.w;
        s1.x += a1.x; s1.y += a1.y; s1.z += a1.z; s1.w += a1.w;
        q0.x += c0.x; q0.y += c0.y; q0.z += c0.z; q0.w += c0.w;
        q1.x += c1.x; q1.y += c1.y; q1.z += c1.z; q1.w += c1.w;
    }

    float4 g0 = gamma4[2 * g], g1 = gamma4[2 * g + 1];
    float4 b0 = beta4[2 * g],  b1 = beta4[2 * g + 1];

    uint4 p = preb4[idx];
    float4 h0 = h4[2 * idx], h1 = h4[2 * idx + 1];
    float4 o0, o1;
    float m, var, sc;

    m = s0.x * invN; var = q0.x * invN - m * m; sc = g0.x * rsqrtf(var + BN_EPS);
    o0.x = h0.x + (bflo(p.x) - m) * sc + b0.x;
    m = s0.y * invN; var = q0.y * invN - m * m; sc = g0.y * rsqrtf(var + BN_EPS);
    o0.y = h0.y + (bfhi(p.x) - m) * sc + b0.y;
    m = s0.z * invN; var = q0.z * invN - m * m; sc = g0.z * rsqrtf(var + BN_EPS);
    o0.z = h0.z + (bflo(p.y) - m) * sc + b0.z;
    m = s0.w * invN; var = q0.w * invN - m * m; sc = g0.w * rsqrtf(var + BN_EPS);
    o0.w = h0.w + (bfhi(p.y) - m) * sc + b0.w;

    m = s1.x * invN; var = q1.x * invN - m * m; sc = g1.x * rsqrtf(var + BN_EPS);
    o1.x = h1.x + (bflo(p.z) - m) * sc + b1.x;
    m = s1.y * invN; var = q1.y * invN - m * m; sc = g1.y * rsqrtf(var + BN_EPS);
    o1.y = h1.y + (bfhi(p.z) - m) * sc + b1.y;
    m = s1.z * invN; var = q1.z * invN - m * m; sc = g1.z * rsqrtf(var + BN_EPS);
    o1.z = h1.z + (bflo(p.w) - m) * sc + b1.z;
    m = s1.w * invN; var = q1.w * invN - m * m; sc = g1.w * rsqrtf(var + BN_EPS);
    o1.w = h1.w + (bfhi(p.w) - m) * sc + b1.w;

    out4[2 * idx]     = o0;
    out4[2 * idx + 1] = o1;
}

// ---------------------------------------------------------------------------
extern "C" void kernel_launch(void* const* d_in, const int* in_sizes, int n_in,
                              void* d_out, int out_size, void* d_ws, size_t ws_size,
                              hipStream_t stream) {
    const float* h      = (const float*)d_in[0];
    const float* snorm  = (const float*)d_in[1];
    const float* Wself  = (const float*)d_in[2];
    const float* Wneigh = (const float*)d_in[3];
    const float* bias   = (const float*)d_in[4];
    const float* gamma  = (const float*)d_in[5];
    const float* beta   = (const float*)d_in[6];
    const int*   src    = (const int*)d_in[7];
    const int*   dst    = (const int*)d_in[8];
    float* out = (float*)d_out;

    // ws layout:
    // zeroed:   [ cursor : N*CSTRIDE int = 5.1MB ][ sums_r : 16*D f ]
    //           [ sumsq_r : 16*D f ]
    // unzeroed: [ esrc : N*CAP int = 20.5MB ][ wfrag : 64KB ]
    //           [ hb : 10.2MB ][ hnb : 10.2MB ][ preb : 10.2MB ][ hb8 : 5.1MB ]
    int*   cursor  = (int*)d_ws;
    float* sums_r  = (float*)(cursor + (size_t)N_NODES * CSTRIDE);
    float* sumsq_r = sums_r + NREP * D;
    int*   esrc    = (int*)(sumsq_r + NREP * D);
    size_t off     = (size_t)((char*)(esrc + (size_t)N_NODES * CAP) - (char*)d_ws);
    off = (off + 15) & ~(size_t)15;
    uint4* wfrag = (uint4*)((char*)d_ws + off);
    uint4* hb4   = wfrag + 4096;
    uint4* hnb4  = hb4 + N_NODES * (D / 8);
    ushort* preb = (ushort*)(hnb4 + N_NODES * (D / 8));
    uint2* hb8   = (uint2*)(preb + (size_t)N_NODES * D);

    size_t zero_bytes = ((size_t)N_NODES * CSTRIDE + 2 * NREP * D) * sizeof(int);
    hipMemsetAsync(d_ws, 0, zero_bytes, stream);

    // K1: colored bucket fill (padded cursor) + h -> bf16/fp8 + W frag-major
    cvt_fill_kernel<<<FILL_BLOCKS, 256, 0, stream>>>(
        dst, src, cursor, esrc, (const float4*)h, hb4, hb8, Wself, Wneigh, wfrag);
    // K2: gather + mean from fp8 -> hnb (bf16), one wave per node, color-pinned
    gather_kernel<<<N_NODES / 4, 256, 0, stream>>>(
        (const uint4*)hb8, cursor, esrc, hnb4);
    // K3: MFMA dual GEMM + relu + snorm + BN partials (16 replicas) -> preb
    gemm_kernel<<<NTILES, 256, 0, stream>>>(hb4, hnb4, wfrag, snorm, bias,
                                            preb, sums_r, sumsq_r);
    // K4: finalize: replica-reduce + residual + BN -> d_out
    final_kernel<<<(N_NODES * D / 8 + 255) / 256, 256, 0, stream>>>(
        (const float4*)h, (const float4*)sums_r, (const float4*)sumsq_r,
        (const float4*)gamma, (const float4*)beta, (const uint4*)preb,
        (float4*)out);
}

// Round 10
// 169.282 us; speedup vs baseline: 1.6491x; 1.0494x over previous
//
#include <hip/hip_runtime.h>
#include <hip/hip_bf16.h>

constexpr int N_NODES = 40000;
constexpr int N_EDGES = 640000;
constexpr int D = 128;
constexpr float BN_EPS = 1e-5f;
constexpr int CAP = 128;          // per-node edge bucket capacity (max deg ~40)
constexpr int NTILES = 1250;      // 625 rowtiles x 2 col-halves
constexpr int NCOLOR = 8;         // XCD colors
constexpr int NODES_PER_COLOR = N_NODES / NCOLOR;   // 5000
constexpr int FILL_BLOCKS = 2560; // 8 colors x 320 ranks
constexpr int COLOR_STRIDE = (FILL_BLOCKS / NCOLOR) * 256;  // 81920
constexpr int NREP = 8;           // BN partial replicas (atomic de-contention)

typedef __attribute__((ext_vector_type(8))) short short8;
typedef __attribute__((ext_vector_type(4))) float f32x4;
typedef __attribute__((ext_vector_type(2))) float f32x2;

__device__ __forceinline__ unsigned bf16_rne(float f) {
    unsigned b = __float_as_uint(f);
    return (b + 0x7FFFu + ((b >> 16) & 1u)) >> 16;
}
__device__ __forceinline__ float bflo(unsigned w) { return __uint_as_float(w << 16); }
__device__ __forceinline__ float bfhi(unsigned w) { return __uint_as_float(w & 0xFFFF0000u); }

// ---------------------------------------------------------------------------
// K1: fused h->bf16 + h->fp8 / W->frag-major conversion + XCD-COLORED bucket
// fill. (exact round-5 version -- verified 168.7us config)
// ---------------------------------------------------------------------------
__global__ __launch_bounds__(256) void cvt_fill_kernel(
        const int* __restrict__ dst,
        const int* __restrict__ src,
        int* __restrict__ cursor,
        int* __restrict__ esrc,
        const float4* __restrict__ h4,
        uint4* __restrict__ hb4,
        uint2* __restrict__ hb8,
        const float* __restrict__ Wself,
        const float* __restrict__ Wneigh,
        uint4* __restrict__ wfrag) {
    int gid = blockIdx.x * blockDim.x + threadIdx.x;

    if (gid < N_EDGES) {
        float4 a = h4[2 * gid];
        float4 b = h4[2 * gid + 1];
        uint4 o;
        o.x = bf16_rne(a.x) | (bf16_rne(a.y) << 16);
        o.y = bf16_rne(a.z) | (bf16_rne(a.w) << 16);
        o.z = bf16_rne(b.x) | (bf16_rne(b.y) << 16);
        o.w = bf16_rne(b.z) | (bf16_rne(b.w) << 16);
        hb4[gid] = o;
        unsigned w0 = __builtin_amdgcn_cvt_pk_fp8_f32(a.x, a.y, 0, false);
        w0 = __builtin_amdgcn_cvt_pk_fp8_f32(a.z, a.w, w0, true);
        unsigned w1 = __builtin_amdgcn_cvt_pk_fp8_f32(b.x, b.y, 0, false);
        w1 = __builtin_amdgcn_cvt_pk_fp8_f32(b.z, b.w, w1, true);
        uint2 o8; o8.x = w0; o8.y = w1;
        hb8[gid] = o8;
    }
    // W -> frag-major bf16: granule G=(ct*8+kt)*64+kg*16+n holds j=0..7 of
    // Wcat[k=kt*32+kg*8+j][col=ct*16+n], Wcat=[Wself;Wneigh] (K=256).
    if (gid < 4096) {
        int G = gid;
        int l = G & 63;
        int tile = G >> 6;
        int kg = l >> 4, n = l & 15;
        int ct = tile >> 3, kt = tile & 7;
        int k0 = kt * 32 + kg * 8;
        int col = ct * 16 + n;
        unsigned w[8];
        #pragma unroll
        for (int j = 0; j < 8; j++) {
            int k = k0 + j;
            float v = (k < D) ? Wself[(size_t)k * D + col]
                              : Wneigh[(size_t)(k - D) * D + col];
            w[j] = bf16_rne(v);
        }
        uint4 ow;
        ow.x = w[0] | (w[1] << 16);
        ow.y = w[2] | (w[3] << 16);
        ow.z = w[4] | (w[5] << 16);
        ow.w = w[6] | (w[7] << 16);
        wfrag[G] = ow;
    }

    // colored bucket fill
    int c = blockIdx.x & (NCOLOR - 1);
    int lo = c * NODES_PER_COLOR;
    int hi = lo + NODES_PER_COLOR;
    int base = (blockIdx.x >> 3) * 256 + threadIdx.x;
    for (int e = base; e < N_EDGES; e += COLOR_STRIDE) {
        int t = dst[e];
        if (t >= lo && t < hi) {
            int s = src[e];
            int p = atomicAdd(&cursor[t], 1);
            if (p < CAP) esrc[t * CAP + p] = s;
        }
    }
}

// ---------------------------------------------------------------------------
// K2: gather + mean from fp8 rows, one wave per node, COLOR-PINNED.
// (exact round-5 version)
// ---------------------------------------------------------------------------
__global__ __launch_bounds__(256) void gather_kernel(
        const uint4* __restrict__ hb8q,   // 8 uint4 per node row (128 fp8)
        const int* __restrict__ cursor,
        const int* __restrict__ esrc,
        uint4* __restrict__ hnb4) {
    int c = blockIdx.x & (NCOLOR - 1);
    int rank = blockIdx.x >> 3;           // 0..1249
    int wid = threadIdx.x >> 6;
    int node = c * NODES_PER_COLOR + rank * 4 + wid;
    int lane = threadIdx.x & 63;
    int g  = lane & 7;        // 16-col group
    int es = lane >> 3;       // 8 edge slices
    int deg = cursor[node];
    int cnt = deg < CAP ? deg : CAP;
    const int* bucket = esrc + node * CAP;
    float acc[16];
    #pragma unroll
    for (int i = 0; i < 16; i++) acc[i] = 0.f;
    for (int j = es; j < cnt; j += 8) {
        int a = bucket[j];
        uint4 v = hb8q[(size_t)a * 8 + g];
        f32x2 f;
        f = __builtin_amdgcn_cvt_pk_f32_fp8(v.x, false); acc[0]  += f.x; acc[1]  += f.y;
        f = __builtin_amdgcn_cvt_pk_f32_fp8(v.x, true);  acc[2]  += f.x; acc[3]  += f.y;
        f = __builtin_amdgcn_cvt_pk_f32_fp8(v.y, false); acc[4]  += f.x; acc[5]  += f.y;
        f = __builtin_amdgcn_cvt_pk_f32_fp8(v.y, true);  acc[6]  += f.x; acc[7]  += f.y;
        f = __builtin_amdgcn_cvt_pk_f32_fp8(v.z, false); acc[8]  += f.x; acc[9]  += f.y;
        f = __builtin_amdgcn_cvt_pk_f32_fp8(v.z, true);  acc[10] += f.x; acc[11] += f.y;
        f = __builtin_amdgcn_cvt_pk_f32_fp8(v.w, false); acc[12] += f.x; acc[13] += f.y;
        f = __builtin_amdgcn_cvt_pk_f32_fp8(v.w, true);  acc[14] += f.x; acc[15] += f.y;
    }
    #pragma unroll
    for (int i = 0; i < 16; i++) {
        acc[i] += __shfl_xor(acc[i], 8);
        acc[i] += __shfl_xor(acc[i], 16);
        acc[i] += __shfl_xor(acc[i], 32);
    }
    if (es == 0) {
        float rd = 1.0f / (float)(deg > 1 ? deg : 1);
        uint4 o0, o1;
        o0.x = bf16_rne(acc[0] * rd)  | (bf16_rne(acc[1] * rd)  << 16);
        o0.y = bf16_rne(acc[2] * rd)  | (bf16_rne(acc[3] * rd)  << 16);
        o0.z = bf16_rne(acc[4] * rd)  | (bf16_rne(acc[5] * rd)  << 16);
        o0.w = bf16_rne(acc[6] * rd)  | (bf16_rne(acc[7] * rd)  << 16);
        o1.x = bf16_rne(acc[8] * rd)  | (bf16_rne(acc[9] * rd)  << 16);
        o1.y = bf16_rne(acc[10] * rd) | (bf16_rne(acc[11] * rd) << 16);
        o1.z = bf16_rne(acc[12] * rd) | (bf16_rne(acc[13] * rd) << 16);
        o1.w = bf16_rne(acc[14] * rd) | (bf16_rne(acc[15] * rd) << 16);
        hnb4[(size_t)node * 16 + g * 2]     = o0;
        hnb4[(size_t)node * 16 + g * 2 + 1] = o1;
    }
}

// ---------------------------------------------------------------------------
// K3: MFMA dual GEMM, BN partials to 8 replicas (replica = blockIdx&7,
// matching XCD round-robin). pre stored bf16 in ws. (exact round-5 version)
// ---------------------------------------------------------------------------
__global__ __launch_bounds__(256) void gemm_kernel(
        const uint4* __restrict__ hb4,
        const uint4* __restrict__ hnb4,
        const uint4* __restrict__ wfrag,
        const float* __restrict__ snorm,
        const float* __restrict__ bias,
        ushort* __restrict__ preb,          // bf16 pre (ws)
        float* __restrict__ sums_r,         // [NREP][D]
        float* __restrict__ sumsq_r) {      // [NREP][D]
    __shared__ uint4 ldsW[2048];
    __shared__ float sums_l[64];
    __shared__ float sumsq_l[64];

    int t = threadIdx.x;
    int lane = t & 63;
    int wid = t >> 6;
    int n = lane & 15;
    int kg = lane >> 4;
    int rowtile = blockIdx.x >> 1;
    int cbt = blockIdx.x & 1;
    int cb = cbt * 64;
    int row_base = rowtile * 64 + wid * 16;
    int row = row_base + n;

    if (t < 64) { sums_l[t] = 0.f; sumsq_l[t] = 0.f; }

    short8 a[8];
    #pragma unroll
    for (int kt = 0; kt < 4; kt++) {
        uint4 v = hb4[(size_t)row * 16 + kt * 4 + kg];
        a[kt] = __builtin_bit_cast(short8, v);
    }
    #pragma unroll
    for (int kt = 0; kt < 4; kt++) {
        uint4 v = hnb4[(size_t)row * 16 + kt * 4 + kg];
        a[4 + kt] = __builtin_bit_cast(short8, v);
    }

    #pragma unroll
    for (int i = 0; i < 8; i++) {
        int g = i * 256 + t;
        ldsW[g] = wfrag[cbt * 2048 + g];
    }
    __syncthreads();

    f32x4 acc[4];
    #pragma unroll
    for (int lt = 0; lt < 4; lt++) acc[lt] = (f32x4){0.f, 0.f, 0.f, 0.f};
    #pragma unroll
    for (int lt = 0; lt < 4; lt++) {
        #pragma unroll
        for (int kt = 0; kt < 8; kt++) {
            short8 b = __builtin_bit_cast(short8, ldsW[(lt * 8 + kt) * 64 + lane]);
            acc[lt] = __builtin_amdgcn_mfma_f32_16x16x32_bf16(a[kt], b, acc[lt], 0, 0, 0);
        }
    }

    float snv[4];
    #pragma unroll
    for (int r = 0; r < 4; r++) snv[r] = snorm[row_base + kg * 4 + r];

    #pragma unroll
    for (int lt = 0; lt < 4; lt++) {
        int col = cb + lt * 16 + n;
        float bb = bias[col];
        float csum = 0.f, csq = 0.f;
        #pragma unroll
        for (int r = 0; r < 4; r++) {
            int rr = row_base + kg * 4 + r;
            float v = acc[lt][r] + bb;
            v = fmaxf(v, 0.f);
            v *= snv[r];
            preb[(size_t)rr * D + col] = (ushort)bf16_rne(v);
            csum += v;
            csq += v * v;
        }
        csum += __shfl_xor(csum, 16); csq += __shfl_xor(csq, 16);
        csum += __shfl_xor(csum, 32); csq += __shfl_xor(csq, 32);
        if (kg == 0) {
            atomicAdd(&sums_l[lt * 16 + n], csum);
            atomicAdd(&sumsq_l[lt * 16 + n], csq);
        }
    }
    __syncthreads();
    if (t < 64) {
        int rep = blockIdx.x & (NREP - 1);
        atomicAdd(&sums_r[rep * D + cb + t], sums_l[t]);
        atomicAdd(&sumsq_r[rep * D + cb + t], sumsq_l[t]);
    }
}

// ---------------------------------------------------------------------------
// K4: finalize: replica-reduce (8) + residual + BN from bf16 pre -> d_out.
// (exact round-5 version)
// ---------------------------------------------------------------------------
__global__ __launch_bounds__(256) void final_kernel(
        const float4* __restrict__ h4,
        const float4* __restrict__ sums_r4,    // [NREP][32] float4
        const float4* __restrict__ sumsq_r4,   // [NREP][32] float4
        const float4* __restrict__ gamma4,
        const float4* __restrict__ beta4,
        const uint4* __restrict__ preb4,
        float4* __restrict__ out4) {
    int idx = blockIdx.x * blockDim.x + threadIdx.x;
    int total = N_NODES * D / 8;
    if (idx >= total) return;
    int g = idx & 15;                       // col-group of 8 within the row
    const float invN = 1.0f / (float)N_NODES;

    float4 s0 = {0.f,0.f,0.f,0.f}, s1 = {0.f,0.f,0.f,0.f};
    float4 q0 = {0.f,0.f,0.f,0.f}, q1 = {0.f,0.f,0.f,0.f};
    #pragma unroll
    for (int r = 0; r < NREP; r++) {
        float4 a0 = sums_r4[r * 32 + 2 * g],  a1 = sums_r4[r * 32 + 2 * g + 1];
        float4 c0 = sumsq_r4[r * 32 + 2 * g], c1 = sumsq_r4[r * 32 + 2 * g + 1];
        s0.x += a0.x; s0.y += a0.y; s0.z += a0.z; s0.w += a0.w;
        s1.x += a1.x; s1.y += a1.y; s1.z += a1.z; s1.w += a1.w;
        q0.x += c0.x; q0.y += c0.y; q0.z += c0.z; q0.w += c0.w;
        q1.x += c1.x; q1.y += c1.y; q1.z += c1.z; q1.w += c1.w;
    }

    float4 g0 = gamma4[2 * g], g1 = gamma4[2 * g + 1];
    float4 b0 = beta4[2 * g],  b1 = beta4[2 * g + 1];

    uint4 p = preb4[idx];
    float4 h0 = h4[2 * idx], h1 = h4[2 * idx + 1];
    float4 o0, o1;
    float m, var, sc;

    m = s0.x * invN; var = q0.x * invN - m * m; sc = g0.x * rsqrtf(var + BN_EPS);
    o0.x = h0.x + (bflo(p.x) - m) * sc + b0.x;
    m = s0.y * invN; var = q0.y * invN - m * m; sc = g0.y * rsqrtf(var + BN_EPS);
    o0.y = h0.y + (bfhi(p.x) - m) * sc + b0.y;
    m = s0.z * invN; var = q0.z * invN - m * m; sc = g0.z * rsqrtf(var + BN_EPS);
    o0.z = h0.z + (bflo(p.y) - m) * sc + b0.z;
    m = s0.w * invN; var = q0.w * invN - m * m; sc = g0.w * rsqrtf(var + BN_EPS);
    o0.w = h0.w + (bfhi(p.y) - m) * sc + b0.w;

    m = s1.x * invN; var = q1.x * invN - m * m; sc = g1.x * rsqrtf(var + BN_EPS);
    o1.x = h1.x + (bflo(p.z) - m) * sc + b1.x;
    m = s1.y * invN; var = q1.y * invN - m * m; sc = g1.y * rsqrtf(var + BN_EPS);
    o1.y = h1.y + (bfhi(p.z) - m) * sc + b1.y;
    m = s1.z * invN; var = q1.z * invN - m * m; sc = g1.z * rsqrtf(var + BN_EPS);
    o1.z = h1.z + (bflo(p.w) - m) * sc + b1.z;
    m = s1.w * invN; var = q1.w * invN - m * m; sc = g1.w * rsqrtf(var + BN_EPS);
    o1.w = h1.w + (bfhi(p.w) - m) * sc + b1.w;

    out4[2 * idx]     = o0;
    out4[2 * idx + 1] = o1;
}

// ---------------------------------------------------------------------------
extern "C" void kernel_launch(void* const* d_in, const int* in_sizes, int n_in,
                              void* d_out, int out_size, void* d_ws, size_t ws_size,
                              hipStream_t stream) {
    const float* h      = (const float*)d_in[0];
    const float* snorm  = (const float*)d_in[1];
    const float* Wself  = (const float*)d_in[2];
    const float* Wneigh = (const float*)d_in[3];
    const float* bias   = (const float*)d_in[4];
    const float* gamma  = (const float*)d_in[5];
    const float* beta   = (const float*)d_in[6];
    const int*   src    = (const int*)d_in[7];
    const int*   dst    = (const int*)d_in[8];
    float* out = (float*)d_out;

    // ws layout:
    // zeroed:   [ cursor : N int ][ sums_r : 8*D f ][ sumsq_r : 8*D f ]
    // unzeroed: [ esrc : N*CAP int = 20.5MB ][ wfrag : 64KB ]
    //           [ hb : 10.2MB ][ hnb : 10.2MB ][ preb : 10.2MB ][ hb8 : 5.1MB ]
    int*   cursor  = (int*)d_ws;
    float* sums_r  = (float*)(cursor + N_NODES);
    float* sumsq_r = sums_r + NREP * D;
    int*   esrc    = (int*)(sumsq_r + NREP * D);
    size_t off     = (size_t)((char*)(esrc + (size_t)N_NODES * CAP) - (char*)d_ws);
    off = (off + 15) & ~(size_t)15;
    uint4* wfrag = (uint4*)((char*)d_ws + off);
    uint4* hb4   = wfrag + 4096;
    uint4* hnb4  = hb4 + N_NODES * (D / 8);
    ushort* preb = (ushort*)(hnb4 + N_NODES * (D / 8));
    uint2* hb8   = (uint2*)(preb + (size_t)N_NODES * D);

    size_t zero_bytes = (size_t)(N_NODES + 2 * NREP * D) * sizeof(float);
    hipMemsetAsync(d_ws, 0, zero_bytes, stream);

    // K1: colored bucket fill + h -> bf16/fp8 + W -> frag-major bf16
    cvt_fill_kernel<<<FILL_BLOCKS, 256, 0, stream>>>(
        dst, src, cursor, esrc, (const float4*)h, hb4, hb8, Wself, Wneigh, wfrag);
    // K2: gather + mean from fp8 -> hnb (bf16), one wave per node, color-pinned
    gather_kernel<<<N_NODES / 4, 256, 0, stream>>>(
        (const uint4*)hb8, cursor, esrc, hnb4);
    // K3: MFMA dual GEMM + relu + snorm + BN partials (8 replicas) -> preb
    gemm_kernel<<<NTILES, 256, 0, stream>>>(hb4, hnb4, wfrag, snorm, bias,
                                            preb, sums_r, sumsq_r);
    // K4: finalize: replica-reduce + residual + BN -> d_out
    final_kernel<<<(N_NODES * D / 8 + 255) / 256, 256, 0, stream>>>(
        (const float4*)h, (const float4*)sums_r, (const float4*)sumsq_r,
        (const float4*)gamma, (const float4*)beta, (const uint4*)preb,
        (float4*)out);
}